// Round 6
// baseline (459.364 us; speedup 1.0000x reference)
//
#include <hip/hip_runtime.h>
#include <cstdint>
#include <cstddef>

typedef __attribute__((ext_vector_type(8))) unsigned short us8;
typedef __attribute__((ext_vector_type(8))) short short8;
typedef __attribute__((ext_vector_type(4))) float f4v;

#define B_ 4
#define C_ 384
#define H_ 224
#define W_ 224
#define HH 28
#define WW 28
#define HW_ (H_*W_)
#define M_ (HH*WW)
#define SCALE_ 0.05103103630798288f   // 1/sqrt(384)
#define EPS_ 1e-12f

__device__ __forceinline__ unsigned short f2bf(float f) {
    union { float f; unsigned int u; } v; v.f = f;
    unsigned int r = v.u + 0x7FFFu + ((v.u >> 16) & 1u);
    return (unsigned short)(r >> 16);
}
__device__ __forceinline__ float bf2f(unsigned short h) {
    union { unsigned int u; float f; } v; v.u = ((unsigned int)h) << 16;
    return v.f;
}

// ---------------------------------------------------------------------------
// k_tp: layout transform + pool, no LDS. Block = (b, py, cgroup of 32 ch),
// 896 threads = (w 0..223) x (oct 0..3).
// ---------------------------------------------------------------------------
__global__ __launch_bounds__(896) void k_tp(const float* __restrict__ x,
                                            unsigned short* __restrict__ pix,
                                            unsigned short* __restrict__ stokenBF) {
    int bid = blockIdx.x;
    int cg = bid % 12; int t2 = bid / 12; int py = t2 % HH; int b = t2 / HH;
    int tid = threadIdx.x;
    int w = tid >> 2;          // 0..223
    int oct = tid & 3;         // 0..3
    int pxx = w >> 3, qq = w & 7;
    int cbase = cg * 32 + oct * 8;

    const float* xb = x + ((size_t)(b * C_ + cbase) * H_ + py * 8) * W_ + w;
    unsigned short* pb = pix + (((size_t)b * M_ + py * WW + pxx) * 64) * C_ + cbase;

    float v[8][8];   // [pp][j]
    #pragma unroll
    for (int j = 0; j < 8; ++j)
        #pragma unroll
        for (int pp = 0; pp < 8; ++pp)
            v[pp][j] = xb[(size_t)j * HW_ + (size_t)pp * W_];

    #pragma unroll
    for (int pp = 0; pp < 8; ++pp) {
        us8 o;
        #pragma unroll
        for (int j = 0; j < 8; ++j) o[j] = f2bf(v[pp][j]);
        *(us8*)(pb + (size_t)(pp * 8 + qq) * C_) = o;
    }

    float psum[8];
    #pragma unroll
    for (int j = 0; j < 8; ++j) {
        float s = 0.f;
        #pragma unroll
        for (int pp = 0; pp < 8; ++pp) s += v[pp][j];
        s += __shfl_xor(s, 4);
        s += __shfl_xor(s, 8);
        s += __shfl_xor(s, 16);
        psum[j] = s;
    }
    int lane = tid & 63;
    if ((lane & 28) == 0) {    // one lane per (patch, oct)
        us8 o;
        #pragma unroll
        for (int j = 0; j < 8; ++j) o[j] = f2bf(psum[j] * (1.f / 64.f));
        *(us8*)(stokenBF + ((size_t)b * M_ + py * WW + pxx) * C_ + cbase) = o;
    }
}

// ---------------------------------------------------------------------------
// QK via MFMA (m89-verified D mapping: col=lane&15, row=(lane>>4)*4+reg).
// ---------------------------------------------------------------------------
__device__ __forceinline__ f4v qk_wave(const unsigned short* __restrict__ pixP,
                                       const unsigned short* __restrict__ bfbase,
                                       int b, int py, int pxx, int mt) {
    int lane = threadIdx.x & 63;
    int n = lane & 15, g = lane >> 4;
    int yy = py + n / 3 - 1, xx = pxx + n % 3 - 1;
    bool valid = (n < 9) && yy >= 0 && yy < HH && xx >= 0 && xx < WW;
    size_t cell = valid ? ((size_t)b * M_ + (size_t)yy * WW + xx) : 0;
    const unsigned short* bp = bfbase + cell * C_ + g * 8;
    const unsigned short* ap = pixP + (size_t)(mt * 16 + n) * C_ + g * 8;
    const short8 zz = {0, 0, 0, 0, 0, 0, 0, 0};
    f4v acc = {0.f, 0.f, 0.f, 0.f};
    #pragma unroll
    for (int kt = 0; kt < 12; ++kt) {
        short8 a = *(const short8*)(ap + kt * 32);
        short8 bv = *(const short8*)(bp + kt * 32);
        if (!valid) bv = zz;
        acc = __builtin_amdgcn_mfma_f32_16x16x32_bf16(a, bv, acc, 0, 0, 0);
    }
    return acc;
}

__device__ __forceinline__ void softmax_wave(const f4v s, float aout[4]) {
    int lane = threadIdx.x & 63;
    bool coln = (lane & 15) < 9;
    float v[4], e[4], mx[4], su[4];
    #pragma unroll
    for (int r = 0; r < 4; ++r) v[r] = coln ? s[r] * SCALE_ : -3e38f;
    #pragma unroll
    for (int r = 0; r < 4; ++r) mx[r] = v[r];
    #pragma unroll
    for (int d = 1; d < 16; d <<= 1)
        #pragma unroll
        for (int r = 0; r < 4; ++r) mx[r] = fmaxf(mx[r], __shfl_xor(mx[r], d));
    #pragma unroll
    for (int r = 0; r < 4; ++r) e[r] = coln ? __expf(v[r] - mx[r]) : 0.f;
    #pragma unroll
    for (int r = 0; r < 4; ++r) su[r] = e[r];
    #pragma unroll
    for (int d = 1; d < 16; d <<= 1)
        #pragma unroll
        for (int r = 0; r < 4; ++r) su[r] += __shfl_xor(su[r], d);
    #pragma unroll
    for (int r = 0; r < 4; ++r) aout[r] = e[r] / su[r];
}

// ---------------------------------------------------------------------------
// k_it0: iteration 0. Block per (b,patch), 4 waves = 4 M-tiles.
// ---------------------------------------------------------------------------
__global__ __launch_bounds__(256) void k_it0(const unsigned short* __restrict__ pix,
                                             const unsigned short* __restrict__ stokenBF,
                                             float* __restrict__ st_part,
                                             float* __restrict__ normpart) {
    int bid = blockIdx.x;
    int m = bid % M_, b = bid / M_;
    int py = m / WW, pxx = m - py * WW;
    int tid = threadIdx.x;
    int wid = tid >> 6, lane = tid & 63;
    int n = lane & 15, g = lane >> 4;

    __shared__ float aff32[64][12];
    __shared__ float npart[4][16];

    const unsigned short* pixP = pix + (size_t)bid * 64 * C_;
    f4v s = qk_wave(pixP, stokenBF, b, py, pxx, wid);
    float a[4];
    softmax_wave(s, a);

    if (n < 9) {
        #pragma unroll
        for (int r = 0; r < 4; ++r) aff32[wid * 16 + g * 4 + r][n] = a[r];
    }
    float p = a[0] + a[1] + a[2] + a[3];
    p += __shfl_xor(p, 16);
    p += __shfl_xor(p, 32);
    if (lane < 9) npart[wid][lane] = p;
    __syncthreads();

    if (tid < 9)
        normpart[(size_t)bid * 9 + tid] =
            npart[0][tid] + npart[1][tid] + npart[2][tid] + npart[3][tid];

    for (int c = tid; c < C_; c += 256) {
        float acc9[9];
        #pragma unroll
        for (int k = 0; k < 9; ++k) acc9[k] = 0.f;
        const unsigned short* pb = pixP + c;
        for (int l = 0; l < 64; ++l) {
            float pv = bf2f(pb[(size_t)l * C_]);
            const float4* arow = (const float4*)aff32[l];
            float4 a0 = arow[0], a1 = arow[1];
            float a8 = aff32[l][8];
            acc9[0] += pv * a0.x; acc9[1] += pv * a0.y;
            acc9[2] += pv * a0.z; acc9[3] += pv * a0.w;
            acc9[4] += pv * a1.x; acc9[5] += pv * a1.y;
            acc9[6] += pv * a1.z; acc9[7] += pv * a1.w;
            acc9[8] += pv * a8;
        }
        #pragma unroll
        for (int k = 0; k < 9; ++k)
            st_part[((size_t)bid * 9 + k) * C_ + c] = acc9[k];
    }
}

// ---------------------------------------------------------------------------
// k_fold: gather-fold st_part into refined stokens (pre-divided by norm).
// ---------------------------------------------------------------------------
__global__ __launch_bounds__(256) void k_fold(const float* __restrict__ st_part,
                                              const float* __restrict__ normpart,
                                              float* __restrict__ refined,
                                              unsigned short* __restrict__ refinedBF) {
    int bid = blockIdx.x;
    int cell = bid % M_, b = bid / M_;
    int cy = cell / WW, cx = cell - cy * WW;
    int tid = threadIdx.x;

    float nsum = 0.f;
    int srcm[9]; int nsrc = 0;
    #pragma unroll
    for (int nn = 0; nn < 9; ++nn) {
        int my = cy - (nn / 3 - 1), mx = cx - (nn % 3 - 1);
        if (my >= 0 && my < HH && mx >= 0 && mx < WW) {
            int mm = my * WW + mx;
            srcm[nsrc] = mm * 9 + nn;
            nsum += normpart[(size_t)b * M_ * 9 + mm * 9 + nn];
            ++nsrc;
        }
    }
    float inv = 1.f / (nsum + EPS_);
    for (int c = tid; c < C_; c += 256) {
        float s = 0.f;
        for (int k = 0; k < nsrc; ++k)
            s += st_part[((size_t)b * M_ * 9 + srcm[k]) * C_ + c];
        float r = s * inv;
        refined[((size_t)b * M_ + cell) * C_ + c] = r;
        refinedBF[((size_t)b * M_ + cell) * C_ + c] = f2bf(r);
    }
}

// ---------------------------------------------------------------------------
// k_aff: iteration-1 affinity. Writes TRANSPOSED afft[b][py][pp][n][224]
// (w fastest) so k_out reads are wave-coalesced.
// ---------------------------------------------------------------------------
__global__ __launch_bounds__(256) void k_aff(const unsigned short* __restrict__ pix,
                                             const unsigned short* __restrict__ refinedBF,
                                             float* __restrict__ afft) {
    int bid = blockIdx.x;
    int m = bid % M_, b = bid / M_;
    int py = m / WW, pxx = m - py * WW;
    int tid = threadIdx.x;
    int wid = tid >> 6, lane = tid & 63;
    int n = lane & 15, g = lane >> 4;

    const unsigned short* pixP = pix + (size_t)bid * 64 * C_;
    f4v s = qk_wave(pixP, refinedBF, b, py, pxx, wid);
    float a[4];
    softmax_wave(s, a);

    if (n < 9) {
        #pragma unroll
        for (int r = 0; r < 4; ++r) {
            int l = wid * 16 + g * 4 + r;
            int pp = l >> 3, qq = l & 7;
            afft[((((size_t)b * HH + py) * 8 + pp) * 9 + n) * W_ + pxx * 8 + qq] = a[r];
        }
    }
}

// ---------------------------------------------------------------------------
// k_out: broadcast. Block = (b, py, w-half of 112), 896 threads =
// (ci 0..7) x (w 0..111). ALL 384 channels per block:
//  - afft read exactly once (72 coalesced scalar loads -> 72 regs, reused
//    across 48 channels/thread; pp/nn fully unrolled for static reg indexing)
//  - refined staged once per block in padded LDS stub [3][16][388]
//  - stores full-line: 112 consecutive w = 448B = 7 aligned 64B lines
// ---------------------------------------------------------------------------
__global__ __launch_bounds__(896) void k_out(const float* __restrict__ refined,
                                             const float* __restrict__ afft,
                                             float* __restrict__ out) {
    int bid = blockIdx.x;
    int half = bid & 1; int t2 = bid >> 1; int py = t2 % HH; int b = t2 / HH;
    int tid = threadIdx.x;
    int w = tid % 112, ci = tid / 112;       // ci 0..7
    int pxx = w >> 3;                        // local patch 0..13

    __shared__ float stub[3 * 16 * 388];     // [row][xxp][ch], pad 388 (=4 mod 32)

    for (int idx = tid; idx < 3 * 16 * 384; idx += 896) {
        int ch = idx % 384; int t = idx / 384;
        int xxp = t % 16; int r = t / 16;
        int yy = py + r - 1, xx = half * 14 + xxp - 1;
        float v = 0.f;
        if (yy >= 0 && yy < HH && xx >= 0 && xx < WW)
            v = refined[((size_t)b * M_ + yy * WW + xx) * C_ + ch];
        stub[(r * 16 + xxp) * 388 + ch] = v;
    }

    // hoist affinity: an[pp][nn], coalesced plane loads (once per value)
    float an[8][9];
    const float* ab = afft + (((size_t)b * HH + py) * 8) * 9 * W_ + half * 112 + w;
    #pragma unroll
    for (int pp = 0; pp < 8; ++pp)
        #pragma unroll
        for (int nn = 0; nn < 9; ++nn)
            an[pp][nn] = ab[(size_t)(pp * 9 + nn) * W_];
    __syncthreads();

    float* ob = out + ((size_t)b * C_ * H_ + (size_t)py * 8) * W_ + half * 112 + w;

    for (int kq = 0; kq < 12; ++kq) {
        int ch = ci * 48 + kq * 4;
        float sv[9][4];
        #pragma unroll
        for (int nn = 0; nn < 9; ++nn) {
            int r = nn / 3, dx = nn % 3;
            float4 v4 = *(const float4*)&stub[(r * 16 + pxx + dx) * 388 + ch];
            sv[nn][0] = v4.x; sv[nn][1] = v4.y; sv[nn][2] = v4.z; sv[nn][3] = v4.w;
        }
        #pragma unroll
        for (int pp = 0; pp < 8; ++pp) {
            #pragma unroll
            for (int j = 0; j < 4; ++j) {
                float s = 0.f;
                #pragma unroll
                for (int nn = 0; nn < 9; ++nn) s += sv[nn][j] * an[pp][nn];
                ob[((size_t)(ch + j) * H_ + pp) * W_] = s;
            }
        }
    }
}

// ===========================================================================
// Fallback path (round-1 kernels) if ws_size is too small.
// ===========================================================================
__global__ __launch_bounds__(256) void o_pool(const float* __restrict__ x,
                                              float* __restrict__ stoken) {
    int bid = blockIdx.x;
    int yy = bid % HH;
    int t  = bid / HH;
    int c  = t % C_;
    int b  = t / C_;
    __shared__ float colsum[W_];
    int q = threadIdx.x;
    if (q < W_) {
        const float* base = x + ((size_t)(b * C_ + c) * H_ + yy * 8) * W_ + q;
        float s = 0.f;
        #pragma unroll
        for (int p = 0; p < 8; ++p) s += base[(size_t)p * W_];
        colsum[q] = s;
    }
    __syncthreads();
    if (q < WW) {
        float s = 0.f;
        #pragma unroll
        for (int j = 0; j < 8; ++j) s += colsum[q * 8 + j];
        stoken[(((size_t)b * HH + yy) * WW + q) * C_ + c] = s * (1.f / 64.f);
    }
}

__global__ __launch_bounds__(256) void o_iter0(const float* __restrict__ x,
                                               const float* __restrict__ stoken,
                                               float* __restrict__ raw,
                                               float* __restrict__ norm) {
    int bid = blockIdx.x;
    int m = bid % M_;
    int b = bid / M_;
    int py = m / WW, pxx = m % WW;
    int tid = threadIdx.x;
    int w = tid >> 6, l = tid & 63;
    int pp = l >> 3, qq = l & 7;

    __shared__ unsigned short pixs[C_][66];
    __shared__ float sbuf[2304];
    __shared__ float aff[64][10];
    unsigned short* stub = (unsigned short*)sbuf;

    for (int idx = tid; idx < 9 * C_; idx += 256) {
        int nn = idx / C_, c = idx - nn * C_;
        int yy = py + nn / 3 - 1, xx = pxx + nn % 3 - 1;
        float v = 0.f;
        if (yy >= 0 && yy < HH && xx >= 0 && xx < WW)
            v = stoken[(((size_t)b * HH + yy) * WW + xx) * C_ + c];
        stub[idx] = f2bf(v);
    }
    __syncthreads();

    const float* pxbase = x + (size_t)b * C_ * HW_ + (size_t)(py * 8 + pp) * W_ + (pxx * 8 + qq);
    float acc[9];
    #pragma unroll
    for (int nn = 0; nn < 9; ++nn) acc[nn] = 0.f;
    int c0 = w * 96;
    #pragma unroll 4
    for (int c = c0; c < c0 + 96; ++c) {
        float pv = pxbase[(size_t)c * HW_];
        pixs[c][l] = f2bf(pv);
        #pragma unroll
        for (int nn = 0; nn < 9; ++nn) acc[nn] += pv * bf2f(stub[nn * C_ + c]);
    }
    __syncthreads();
    float* qkred = sbuf;
    #pragma unroll
    for (int nn = 0; nn < 9; ++nn) qkred[tid * 9 + nn] = acc[nn];
    __syncthreads();

    if (tid < 64) {
        float s[9];
        #pragma unroll
        for (int nn = 0; nn < 9; ++nn)
            s[nn] = (qkred[(0 * 64 + tid) * 9 + nn] + qkred[(1 * 64 + tid) * 9 + nn] +
                     qkred[(2 * 64 + tid) * 9 + nn] + qkred[(3 * 64 + tid) * 9 + nn]) * SCALE_;
        float mx = s[0];
        #pragma unroll
        for (int nn = 1; nn < 9; ++nn) mx = fmaxf(mx, s[nn]);
        float den = 0.f;
        #pragma unroll
        for (int nn = 0; nn < 9; ++nn) { float e = __expf(s[nn] - mx); den += e; s[nn] = e; }
        float inv = 1.f / den;
        #pragma unroll
        for (int nn = 0; nn < 9; ++nn) aff[tid][nn] = s[nn] * inv;
    }
    __syncthreads();

    if (tid < 9) {
        float s = 0.f;
        for (int ll = 0; ll < 64; ++ll) s += aff[ll][tid];
        int ty = py + tid / 3 - 1, tx = pxx + tid % 3 - 1;
        if (ty >= 0 && ty < HH && tx >= 0 && tx < WW)
            atomicAdd(&norm[((size_t)b * HH + ty) * WW + tx], s);
    }

    for (int c = tid; c < C_; c += 256) {
        float a2[9];
        #pragma unroll
        for (int nn = 0; nn < 9; ++nn) a2[nn] = 0.f;
        for (int ll = 0; ll < 64; ++ll) {
            float pv = bf2f(pixs[c][ll]);
            #pragma unroll
            for (int nn = 0; nn < 9; ++nn) a2[nn] += pv * aff[ll][nn];
        }
        #pragma unroll
        for (int nn = 0; nn < 9; ++nn) {
            int ty = py + nn / 3 - 1, tx = pxx + nn % 3 - 1;
            if (ty >= 0 && ty < HH && tx >= 0 && tx < WW)
                atomicAdd(&raw[(((size_t)b * HH + ty) * WW + tx) * C_ + c], a2[nn]);
        }
    }
}

__global__ __launch_bounds__(256) void o_final(const float* __restrict__ x,
                                               const float* __restrict__ raw,
                                               const float* __restrict__ norm,
                                               float* __restrict__ out) {
    int bid = blockIdx.x;
    int m = bid % M_;
    int b = bid / M_;
    int py = m / WW, pxx = m % WW;
    int tid = threadIdx.x;
    int w = tid >> 6, l = tid & 63;
    int pp = l >> 3, qq = l & 7;

    __shared__ unsigned short stub[9 * C_];
    __shared__ float qkred[4 * 64 * 9];
    __shared__ float aff[64][10];

    for (int idx = tid; idx < 9 * C_; idx += 256) {
        int nn = idx / C_, c = idx - nn * C_;
        int yy = py + nn / 3 - 1, xx = pxx + nn % 3 - 1;
        float v = 0.f;
        if (yy >= 0 && yy < HH && xx >= 0 && xx < WW) {
            size_t cell = ((size_t)b * HH + yy) * WW + xx;
            v = raw[cell * C_ + c] / (norm[cell] + EPS_);
        }
        stub[idx] = f2bf(v);
    }
    __syncthreads();

    const float* pxbase = x + (size_t)b * C_ * HW_ + (size_t)(py * 8 + pp) * W_ + (pxx * 8 + qq);
    float acc[9];
    #pragma unroll
    for (int nn = 0; nn < 9; ++nn) acc[nn] = 0.f;
    int c0 = w * 96;
    #pragma unroll 4
    for (int c = c0; c < c0 + 96; ++c) {
        float pv = pxbase[(size_t)c * HW_];
        #pragma unroll
        for (int nn = 0; nn < 9; ++nn) acc[nn] += pv * bf2f(stub[nn * C_ + c]);
    }
    #pragma unroll
    for (int nn = 0; nn < 9; ++nn) qkred[tid * 9 + nn] = acc[nn];
    __syncthreads();

    if (tid < 64) {
        float s[9];
        #pragma unroll
        for (int nn = 0; nn < 9; ++nn)
            s[nn] = (qkred[(0 * 64 + tid) * 9 + nn] + qkred[(1 * 64 + tid) * 9 + nn] +
                     qkred[(2 * 64 + tid) * 9 + nn] + qkred[(3 * 64 + tid) * 9 + nn]) * SCALE_;
        float mx = s[0];
        #pragma unroll
        for (int nn = 1; nn < 9; ++nn) mx = fmaxf(mx, s[nn]);
        float den = 0.f;
        #pragma unroll
        for (int nn = 0; nn < 9; ++nn) { float e = __expf(s[nn] - mx); den += e; s[nn] = e; }
        float inv = 1.f / den;
        #pragma unroll
        for (int nn = 0; nn < 9; ++nn) aff[tid][nn] = s[nn] * inv;
    }
    __syncthreads();

    float areg[9];
    #pragma unroll
    for (int nn = 0; nn < 9; ++nn) areg[nn] = aff[l][nn];
    float* obase = out + (size_t)b * C_ * HW_ + (size_t)(py * 8 + pp) * W_ + (pxx * 8 + qq);
    #pragma unroll 4
    for (int c = c0; c < c0 + 96; ++c) {
        float v = 0.f;
        #pragma unroll
        for (int nn = 0; nn < 9; ++nn) v += bf2f(stub[nn * C_ + c]) * areg[nn];
        obase[(size_t)c * HW_] = v;
    }
}

extern "C" void kernel_launch(void* const* d_in, const int* in_sizes, int n_in,
                              void* d_out, int out_size, void* d_ws, size_t ws_size,
                              hipStream_t stream) {
    const float* x = (const float*)d_in[0];
    float* out = (float*)d_out;

    const size_t PIXN = (size_t)B_ * M_ * 64 * C_;      // bf16 elements
    const size_t STN  = (size_t)B_ * M_ * C_;           // elements per stoken set
    const size_t AFFN = (size_t)B_ * HH * 8 * 9 * W_;   // fp32 elements (transposed aff)
    const size_t need = PIXN * 2 + STN * 2 + STN * 2
                      + (STN * 10 + (size_t)B_ * M_ * 9 + AFFN) * 4;

    if (ws_size >= need) {
        unsigned short* pix       = (unsigned short*)d_ws;
        unsigned short* stokenBF  = pix + PIXN;
        unsigned short* refinedBF = stokenBF + STN;
        float* st_part  = (float*)(refinedBF + STN);
        float* refined  = st_part + STN * 9;
        float* normpart = refined + STN;
        float* afft     = normpart + (size_t)B_ * M_ * 9;

        k_tp  <<<B_ * HH * 12, 896, 0, stream>>>(x, pix, stokenBF);
        k_it0 <<<B_ * M_,      256, 0, stream>>>(pix, stokenBF, st_part, normpart);
        k_fold<<<B_ * M_,      256, 0, stream>>>(st_part, normpart, refined, refinedBF);
        k_aff <<<B_ * M_,      256, 0, stream>>>(pix, refinedBF, afft);
        k_out <<<B_ * HH * 2,  896, 0, stream>>>(refined, afft, out);
    } else {
        float* stoken = (float*)d_ws;
        float* raw    = stoken + STN;
        float* norm   = raw + STN;
        hipMemsetAsync(raw, 0, STN * sizeof(float), stream);
        hipMemsetAsync(norm, 0, (size_t)B_ * M_ * sizeof(float), stream);
        o_pool <<<B_ * C_ * HH, 256, 0, stream>>>(x, stoken);
        o_iter0<<<B_ * M_,      256, 0, stream>>>(x, stoken, raw, norm);
        o_final<<<B_ * M_,      256, 0, stream>>>(x, raw, norm, out);
    }
}

// Round 7
// 406.454 us; speedup vs baseline: 1.1302x; 1.1302x over previous
//
#include <hip/hip_runtime.h>
#include <cstdint>
#include <cstddef>

typedef __attribute__((ext_vector_type(8))) unsigned short us8;
typedef __attribute__((ext_vector_type(8))) short short8;
typedef __attribute__((ext_vector_type(4))) float f4v;

#define B_ 4
#define C_ 384
#define H_ 224
#define W_ 224
#define HH 28
#define WW 28
#define HW_ (H_*W_)
#define M_ (HH*WW)
#define SCALE_ 0.05103103630798288f   // 1/sqrt(384)
#define EPS_ 1e-12f

__device__ __forceinline__ unsigned short f2bf(float f) {
    union { float f; unsigned int u; } v; v.f = f;
    unsigned int r = v.u + 0x7FFFu + ((v.u >> 16) & 1u);
    return (unsigned short)(r >> 16);
}
__device__ __forceinline__ float bf2f(unsigned short h) {
    union { unsigned int u; float f; } v; v.u = ((unsigned int)h) << 16;
    return v.f;
}

// ---------------------------------------------------------------------------
// k_tp: layout transform + pool, no LDS. Block = (b, py, cgroup of 32 ch),
// 896 threads = (w 0..223) x (oct 0..3).
// ---------------------------------------------------------------------------
__global__ __launch_bounds__(896) void k_tp(const float* __restrict__ x,
                                            unsigned short* __restrict__ pix,
                                            unsigned short* __restrict__ stokenBF) {
    int bid = blockIdx.x;
    int cg = bid % 12; int t2 = bid / 12; int py = t2 % HH; int b = t2 / HH;
    int tid = threadIdx.x;
    int w = tid >> 2;          // 0..223
    int oct = tid & 3;         // 0..3
    int pxx = w >> 3, qq = w & 7;
    int cbase = cg * 32 + oct * 8;

    const float* xb = x + ((size_t)(b * C_ + cbase) * H_ + py * 8) * W_ + w;
    unsigned short* pb = pix + (((size_t)b * M_ + py * WW + pxx) * 64) * C_ + cbase;

    float v[8][8];   // [pp][j]
    #pragma unroll
    for (int j = 0; j < 8; ++j)
        #pragma unroll
        for (int pp = 0; pp < 8; ++pp)
            v[pp][j] = xb[(size_t)j * HW_ + (size_t)pp * W_];

    #pragma unroll
    for (int pp = 0; pp < 8; ++pp) {
        us8 o;
        #pragma unroll
        for (int j = 0; j < 8; ++j) o[j] = f2bf(v[pp][j]);
        *(us8*)(pb + (size_t)(pp * 8 + qq) * C_) = o;
    }

    float psum[8];
    #pragma unroll
    for (int j = 0; j < 8; ++j) {
        float s = 0.f;
        #pragma unroll
        for (int pp = 0; pp < 8; ++pp) s += v[pp][j];
        s += __shfl_xor(s, 4);
        s += __shfl_xor(s, 8);
        s += __shfl_xor(s, 16);
        psum[j] = s;
    }
    int lane = tid & 63;
    if ((lane & 28) == 0) {    // one lane per (patch, oct)
        us8 o;
        #pragma unroll
        for (int j = 0; j < 8; ++j) o[j] = f2bf(psum[j] * (1.f / 64.f));
        *(us8*)(stokenBF + ((size_t)b * M_ + py * WW + pxx) * C_ + cbase) = o;
    }
}

// ---------------------------------------------------------------------------
// QK via MFMA (m89-verified D mapping: col=lane&15, row=(lane>>4)*4+reg).
// ---------------------------------------------------------------------------
__device__ __forceinline__ f4v qk_wave(const unsigned short* __restrict__ pixP,
                                       const unsigned short* __restrict__ bfbase,
                                       int b, int py, int pxx, int mt) {
    int lane = threadIdx.x & 63;
    int n = lane & 15, g = lane >> 4;
    int yy = py + n / 3 - 1, xx = pxx + n % 3 - 1;
    bool valid = (n < 9) && yy >= 0 && yy < HH && xx >= 0 && xx < WW;
    size_t cell = valid ? ((size_t)b * M_ + (size_t)yy * WW + xx) : 0;
    const unsigned short* bp = bfbase + cell * C_ + g * 8;
    const unsigned short* ap = pixP + (size_t)(mt * 16 + n) * C_ + g * 8;
    const short8 zz = {0, 0, 0, 0, 0, 0, 0, 0};
    f4v acc = {0.f, 0.f, 0.f, 0.f};
    #pragma unroll
    for (int kt = 0; kt < 12; ++kt) {
        short8 a = *(const short8*)(ap + kt * 32);
        short8 bv = *(const short8*)(bp + kt * 32);
        if (!valid) bv = zz;
        acc = __builtin_amdgcn_mfma_f32_16x16x32_bf16(a, bv, acc, 0, 0, 0);
    }
    return acc;
}

__device__ __forceinline__ void softmax_wave(const f4v s, float aout[4]) {
    int lane = threadIdx.x & 63;
    bool coln = (lane & 15) < 9;
    float v[4], e[4], mx[4], su[4];
    #pragma unroll
    for (int r = 0; r < 4; ++r) v[r] = coln ? s[r] * SCALE_ : -3e38f;
    #pragma unroll
    for (int r = 0; r < 4; ++r) mx[r] = v[r];
    #pragma unroll
    for (int d = 1; d < 16; d <<= 1)
        #pragma unroll
        for (int r = 0; r < 4; ++r) mx[r] = fmaxf(mx[r], __shfl_xor(mx[r], d));
    #pragma unroll
    for (int r = 0; r < 4; ++r) e[r] = coln ? __expf(v[r] - mx[r]) : 0.f;
    #pragma unroll
    for (int r = 0; r < 4; ++r) su[r] = e[r];
    #pragma unroll
    for (int d = 1; d < 16; d <<= 1)
        #pragma unroll
        for (int r = 0; r < 4; ++r) su[r] += __shfl_xor(su[r], d);
    #pragma unroll
    for (int r = 0; r < 4; ++r) aout[r] = e[r] / su[r];
}

// ---------------------------------------------------------------------------
// k_it0: iteration 0. Block per (b,patch), 4 waves = 4 M-tiles.
// ---------------------------------------------------------------------------
__global__ __launch_bounds__(256) void k_it0(const unsigned short* __restrict__ pix,
                                             const unsigned short* __restrict__ stokenBF,
                                             float* __restrict__ st_part,
                                             float* __restrict__ normpart) {
    int bid = blockIdx.x;
    int m = bid % M_, b = bid / M_;
    int py = m / WW, pxx = m - py * WW;
    int tid = threadIdx.x;
    int wid = tid >> 6, lane = tid & 63;
    int n = lane & 15, g = lane >> 4;

    __shared__ float aff32[64][12];
    __shared__ float npart[4][16];

    const unsigned short* pixP = pix + (size_t)bid * 64 * C_;
    f4v s = qk_wave(pixP, stokenBF, b, py, pxx, wid);
    float a[4];
    softmax_wave(s, a);

    if (n < 9) {
        #pragma unroll
        for (int r = 0; r < 4; ++r) aff32[wid * 16 + g * 4 + r][n] = a[r];
    }
    float p = a[0] + a[1] + a[2] + a[3];
    p += __shfl_xor(p, 16);
    p += __shfl_xor(p, 32);
    if (lane < 9) npart[wid][lane] = p;
    __syncthreads();

    if (tid < 9)
        normpart[(size_t)bid * 9 + tid] =
            npart[0][tid] + npart[1][tid] + npart[2][tid] + npart[3][tid];

    for (int c = tid; c < C_; c += 256) {
        float acc9[9];
        #pragma unroll
        for (int k = 0; k < 9; ++k) acc9[k] = 0.f;
        const unsigned short* pb = pixP + c;
        for (int l = 0; l < 64; ++l) {
            float pv = bf2f(pb[(size_t)l * C_]);
            const float4* arow = (const float4*)aff32[l];
            float4 a0 = arow[0], a1 = arow[1];
            float a8 = aff32[l][8];
            acc9[0] += pv * a0.x; acc9[1] += pv * a0.y;
            acc9[2] += pv * a0.z; acc9[3] += pv * a0.w;
            acc9[4] += pv * a1.x; acc9[5] += pv * a1.y;
            acc9[6] += pv * a1.z; acc9[7] += pv * a1.w;
            acc9[8] += pv * a8;
        }
        #pragma unroll
        for (int k = 0; k < 9; ++k)
            st_part[((size_t)bid * 9 + k) * C_ + c] = acc9[k];
    }
}

// ---------------------------------------------------------------------------
// k_fold: gather-fold st_part into refined stokens (pre-divided by norm).
// ---------------------------------------------------------------------------
__global__ __launch_bounds__(256) void k_fold(const float* __restrict__ st_part,
                                              const float* __restrict__ normpart,
                                              float* __restrict__ refined,
                                              unsigned short* __restrict__ refinedBF) {
    int bid = blockIdx.x;
    int cell = bid % M_, b = bid / M_;
    int cy = cell / WW, cx = cell - cy * WW;
    int tid = threadIdx.x;

    float nsum = 0.f;
    int srcm[9]; int nsrc = 0;
    #pragma unroll
    for (int nn = 0; nn < 9; ++nn) {
        int my = cy - (nn / 3 - 1), mx = cx - (nn % 3 - 1);
        if (my >= 0 && my < HH && mx >= 0 && mx < WW) {
            int mm = my * WW + mx;
            srcm[nsrc] = mm * 9 + nn;
            nsum += normpart[(size_t)b * M_ * 9 + mm * 9 + nn];
            ++nsrc;
        }
    }
    float inv = 1.f / (nsum + EPS_);
    for (int c = tid; c < C_; c += 256) {
        float s = 0.f;
        for (int k = 0; k < nsrc; ++k)
            s += st_part[((size_t)b * M_ * 9 + srcm[k]) * C_ + c];
        float r = s * inv;
        refined[((size_t)b * M_ + cell) * C_ + c] = r;
        refinedBF[((size_t)b * M_ + cell) * C_ + c] = f2bf(r);
    }
}

// ---------------------------------------------------------------------------
// k_aff: iteration-1 affinity. Writes TRANSPOSED afft[b][py][pp][n][224].
// ---------------------------------------------------------------------------
__global__ __launch_bounds__(256) void k_aff(const unsigned short* __restrict__ pix,
                                             const unsigned short* __restrict__ refinedBF,
                                             float* __restrict__ afft) {
    int bid = blockIdx.x;
    int m = bid % M_, b = bid / M_;
    int py = m / WW, pxx = m - py * WW;
    int tid = threadIdx.x;
    int wid = tid >> 6, lane = tid & 63;
    int n = lane & 15, g = lane >> 4;

    const unsigned short* pixP = pix + (size_t)bid * 64 * C_;
    f4v s = qk_wave(pixP, refinedBF, b, py, pxx, wid);
    float a[4];
    softmax_wave(s, a);

    if (n < 9) {
        #pragma unroll
        for (int r = 0; r < 4; ++r) {
            int l = wid * 16 + g * 4 + r;
            int pp = l >> 3, qq = l & 7;
            afft[((((size_t)b * HH + py) * 8 + pp) * 9 + n) * W_ + pxx * 8 + qq] = a[r];
        }
    }
}

// ---------------------------------------------------------------------------
// k_out v3: block = (b, py, quarter of 56 w), 448 threads = (ci 0..7) x
// (w 0..55). stub fp32 41.9 KB + affs 16.1 KB in LDS (no 72-reg hoist ->
// no spill); kq outer for sv reuse; NONTEMPORAL out stores (no-allocate,
// kills r6's 300 MB write-allocate RMW fetch).
// ---------------------------------------------------------------------------
__global__ __launch_bounds__(448) void k_out(const float* __restrict__ refined,
                                             const float* __restrict__ afft,
                                             float* __restrict__ out) {
    int bid = blockIdx.x;
    int quarter = bid & 3; int t2 = bid >> 2; int py = t2 % HH; int b = t2 / HH;
    int tid = threadIdx.x;
    int w = tid % 56, ci = tid / 56;         // ci 0..7
    int pxl = w >> 3;                        // local patch 0..6

    __shared__ float stub[3 * 9 * 388];      // [row][xxp][ch], pad 388
    __shared__ float affs[8 * 9 * 56];       // [pp][nn][w]

    for (int idx = tid; idx < 3 * 9 * 384; idx += 448) {
        int ch = idx % 384; int t = idx / 384;
        int xxp = t % 9; int r = t / 9;
        int yy = py + r - 1, xx = quarter * 7 + xxp - 1;
        float v = 0.f;
        if (yy >= 0 && yy < HH && xx >= 0 && xx < WW)
            v = refined[((size_t)b * M_ + yy * WW + xx) * C_ + ch];
        stub[(r * 9 + xxp) * 388 + ch] = v;
    }
    const float* abase = afft + (((size_t)b * HH + py) * 8) * 9 * W_ + quarter * 56;
    for (int idx = tid; idx < 8 * 9 * 56; idx += 448) {
        int w2 = idx % 56; int t = idx / 56;   // t = pp*9+nn
        affs[t * 56 + w2] = abase[(size_t)t * W_ + w2];
    }
    __syncthreads();

    float* ob = out + ((size_t)b * C_ * H_ + (size_t)py * 8) * W_ + quarter * 56 + w;

    for (int kq = 0; kq < 12; ++kq) {
        int ch = ci * 48 + kq * 4;
        float sv[9][4];
        #pragma unroll
        for (int nn = 0; nn < 9; ++nn) {
            int r = nn / 3, dx = nn % 3;
            float4 v4 = *(const float4*)&stub[(r * 9 + pxl + dx) * 388 + ch];
            sv[nn][0] = v4.x; sv[nn][1] = v4.y; sv[nn][2] = v4.z; sv[nn][3] = v4.w;
        }
        #pragma unroll
        for (int pp = 0; pp < 8; ++pp) {
            float an[9];
            #pragma unroll
            for (int nn = 0; nn < 9; ++nn)
                an[nn] = affs[(pp * 9 + nn) * 56 + w];
            #pragma unroll
            for (int j = 0; j < 4; ++j) {
                float s = 0.f;
                #pragma unroll
                for (int nn = 0; nn < 9; ++nn) s += sv[nn][j] * an[nn];
                __builtin_nontemporal_store(s, &ob[((size_t)(ch + j) * H_ + pp) * W_]);
            }
        }
    }
}

// ===========================================================================
// Fallback path (round-1 kernels) if ws_size is too small.
// ===========================================================================
__global__ __launch_bounds__(256) void o_pool(const float* __restrict__ x,
                                              float* __restrict__ stoken) {
    int bid = blockIdx.x;
    int yy = bid % HH;
    int t  = bid / HH;
    int c  = t % C_;
    int b  = t / C_;
    __shared__ float colsum[W_];
    int q = threadIdx.x;
    if (q < W_) {
        const float* base = x + ((size_t)(b * C_ + c) * H_ + yy * 8) * W_ + q;
        float s = 0.f;
        #pragma unroll
        for (int p = 0; p < 8; ++p) s += base[(size_t)p * W_];
        colsum[q] = s;
    }
    __syncthreads();
    if (q < WW) {
        float s = 0.f;
        #pragma unroll
        for (int j = 0; j < 8; ++j) s += colsum[q * 8 + j];
        stoken[(((size_t)b * HH + yy) * WW + q) * C_ + c] = s * (1.f / 64.f);
    }
}

__global__ __launch_bounds__(256) void o_iter0(const float* __restrict__ x,
                                               const float* __restrict__ stoken,
                                               float* __restrict__ raw,
                                               float* __restrict__ norm) {
    int bid = blockIdx.x;
    int m = bid % M_;
    int b = bid / M_;
    int py = m / WW, pxx = m % WW;
    int tid = threadIdx.x;
    int w = tid >> 6, l = tid & 63;
    int pp = l >> 3, qq = l & 7;

    __shared__ unsigned short pixs[C_][66];
    __shared__ float sbuf[2304];
    __shared__ float aff[64][10];
    unsigned short* stub = (unsigned short*)sbuf;

    for (int idx = tid; idx < 9 * C_; idx += 256) {
        int nn = idx / C_, c = idx - nn * C_;
        int yy = py + nn / 3 - 1, xx = pxx + nn % 3 - 1;
        float v = 0.f;
        if (yy >= 0 && yy < HH && xx >= 0 && xx < WW)
            v = stoken[(((size_t)b * HH + yy) * WW + xx) * C_ + c];
        stub[idx] = f2bf(v);
    }
    __syncthreads();

    const float* pxbase = x + (size_t)b * C_ * HW_ + (size_t)(py * 8 + pp) * W_ + (pxx * 8 + qq);
    float acc[9];
    #pragma unroll
    for (int nn = 0; nn < 9; ++nn) acc[nn] = 0.f;
    int c0 = w * 96;
    #pragma unroll 4
    for (int c = c0; c < c0 + 96; ++c) {
        float pv = pxbase[(size_t)c * HW_];
        pixs[c][l] = f2bf(pv);
        #pragma unroll
        for (int nn = 0; nn < 9; ++nn) acc[nn] += pv * bf2f(stub[nn * C_ + c]);
    }
    __syncthreads();
    float* qkred = sbuf;
    #pragma unroll
    for (int nn = 0; nn < 9; ++nn) qkred[tid * 9 + nn] = acc[nn];
    __syncthreads();

    if (tid < 64) {
        float s[9];
        #pragma unroll
        for (int nn = 0; nn < 9; ++nn)
            s[nn] = (qkred[(0 * 64 + tid) * 9 + nn] + qkred[(1 * 64 + tid) * 9 + nn] +
                     qkred[(2 * 64 + tid) * 9 + nn] + qkred[(3 * 64 + tid) * 9 + nn]) * SCALE_;
        float mx = s[0];
        #pragma unroll
        for (int nn = 1; nn < 9; ++nn) mx = fmaxf(mx, s[nn]);
        float den = 0.f;
        #pragma unroll
        for (int nn = 0; nn < 9; ++nn) { float e = __expf(s[nn] - mx); den += e; s[nn] = e; }
        float inv = 1.f / den;
        #pragma unroll
        for (int nn = 0; nn < 9; ++nn) aff[tid][nn] = s[nn] * inv;
    }
    __syncthreads();

    if (tid < 9) {
        float s = 0.f;
        for (int ll = 0; ll < 64; ++ll) s += aff[ll][tid];
        int ty = py + tid / 3 - 1, tx = pxx + tid % 3 - 1;
        if (ty >= 0 && ty < HH && tx >= 0 && tx < WW)
            atomicAdd(&norm[((size_t)b * HH + ty) * WW + tx], s);
    }

    for (int c = tid; c < C_; c += 256) {
        float a2[9];
        #pragma unroll
        for (int nn = 0; nn < 9; ++nn) a2[nn] = 0.f;
        for (int ll = 0; ll < 64; ++ll) {
            float pv = bf2f(pixs[c][ll]);
            #pragma unroll
            for (int nn = 0; nn < 9; ++nn) a2[nn] += pv * aff[ll][nn];
        }
        #pragma unroll
        for (int nn = 0; nn < 9; ++nn) {
            int ty = py + nn / 3 - 1, tx = pxx + nn % 3 - 1;
            if (ty >= 0 && ty < HH && tx >= 0 && tx < WW)
                atomicAdd(&raw[(((size_t)b * HH + ty) * WW + tx) * C_ + c], a2[nn]);
        }
    }
}

__global__ __launch_bounds__(256) void o_final(const float* __restrict__ x,
                                               const float* __restrict__ raw,
                                               const float* __restrict__ norm,
                                               float* __restrict__ out) {
    int bid = blockIdx.x;
    int m = bid % M_;
    int b = bid / M_;
    int py = m / WW, pxx = m % WW;
    int tid = threadIdx.x;
    int w = tid >> 6, l = tid & 63;
    int pp = l >> 3, qq = l & 7;

    __shared__ unsigned short stub[9 * C_];
    __shared__ float qkred[4 * 64 * 9];
    __shared__ float aff[64][10];

    for (int idx = tid; idx < 9 * C_; idx += 256) {
        int nn = idx / C_, c = idx - nn * C_;
        int yy = py + nn / 3 - 1, xx = pxx + nn % 3 - 1;
        float v = 0.f;
        if (yy >= 0 && yy < HH && xx >= 0 && xx < WW) {
            size_t cell = ((size_t)b * HH + yy) * WW + xx;
            v = raw[cell * C_ + c] / (norm[cell] + EPS_);
        }
        stub[idx] = f2bf(v);
    }
    __syncthreads();

    const float* pxbase = x + (size_t)b * C_ * HW_ + (size_t)(py * 8 + pp) * W_ + (pxx * 8 + qq);
    float acc[9];
    #pragma unroll
    for (int nn = 0; nn < 9; ++nn) acc[nn] = 0.f;
    int c0 = w * 96;
    #pragma unroll 4
    for (int c = c0; c < c0 + 96; ++c) {
        float pv = pxbase[(size_t)c * HW_];
        #pragma unroll
        for (int nn = 0; nn < 9; ++nn) acc[nn] += pv * bf2f(stub[nn * C_ + c]);
    }
    #pragma unroll
    for (int nn = 0; nn < 9; ++nn) qkred[tid * 9 + nn] = acc[nn];
    __syncthreads();

    if (tid < 64) {
        float s[9];
        #pragma unroll
        for (int nn = 0; nn < 9; ++nn)
            s[nn] = (qkred[(0 * 64 + tid) * 9 + nn] + qkred[(1 * 64 + tid) * 9 + nn] +
                     qkred[(2 * 64 + tid) * 9 + nn] + qkred[(3 * 64 + tid) * 9 + nn]) * SCALE_;
        float mx = s[0];
        #pragma unroll
        for (int nn = 1; nn < 9; ++nn) mx = fmaxf(mx, s[nn]);
        float den = 0.f;
        #pragma unroll
        for (int nn = 0; nn < 9; ++nn) { float e = __expf(s[nn] - mx); den += e; s[nn] = e; }
        float inv = 1.f / den;
        #pragma unroll
        for (int nn = 0; nn < 9; ++nn) aff[tid][nn] = s[nn] * inv;
    }
    __syncthreads();

    float areg[9];
    #pragma unroll
    for (int nn = 0; nn < 9; ++nn) areg[nn] = aff[l][nn];
    float* obase = out + (size_t)b * C_ * HW_ + (size_t)(py * 8 + pp) * W_ + (pxx * 8 + qq);
    #pragma unroll 4
    for (int c = c0; c < c0 + 96; ++c) {
        float v = 0.f;
        #pragma unroll
        for (int nn = 0; nn < 9; ++nn) v += bf2f(stub[nn * C_ + c]) * areg[nn];
        obase[(size_t)c * HW_] = v;
    }
}

extern "C" void kernel_launch(void* const* d_in, const int* in_sizes, int n_in,
                              void* d_out, int out_size, void* d_ws, size_t ws_size,
                              hipStream_t stream) {
    const float* x = (const float*)d_in[0];
    float* out = (float*)d_out;

    const size_t PIXN = (size_t)B_ * M_ * 64 * C_;      // bf16 elements
    const size_t STN  = (size_t)B_ * M_ * C_;           // elements per stoken set
    const size_t AFFN = (size_t)B_ * HH * 8 * 9 * W_;   // fp32 elements (transposed aff)
    const size_t need = PIXN * 2 + STN * 2 + STN * 2
                      + (STN * 10 + (size_t)B_ * M_ * 9 + AFFN) * 4;

    if (ws_size >= need) {
        unsigned short* pix       = (unsigned short*)d_ws;
        unsigned short* stokenBF  = pix + PIXN;
        unsigned short* refinedBF = stokenBF + STN;
        float* st_part  = (float*)(refinedBF + STN);
        float* refined  = st_part + STN * 9;
        float* normpart = refined + STN;
        float* afft     = normpart + (size_t)B_ * M_ * 9;

        k_tp  <<<B_ * HH * 12, 896, 0, stream>>>(x, pix, stokenBF);
        k_it0 <<<B_ * M_,      256, 0, stream>>>(pix, stokenBF, st_part, normpart);
        k_fold<<<B_ * M_,      256, 0, stream>>>(st_part, normpart, refined, refinedBF);
        k_aff <<<B_ * M_,      256, 0, stream>>>(pix, refinedBF, afft);
        k_out <<<B_ * HH * 4,  448, 0, stream>>>(refined, afft, out);
    } else {
        float* stoken = (float*)d_ws;
        float* raw    = stoken + STN;
        float* norm   = raw + STN;
        hipMemsetAsync(raw, 0, STN * sizeof(float), stream);
        hipMemsetAsync(norm, 0, (size_t)B_ * M_ * sizeof(float), stream);
        o_pool <<<B_ * C_ * HH, 256, 0, stream>>>(x, stoken);
        o_iter0<<<B_ * M_,      256, 0, stream>>>(x, stoken, raw, norm);
        o_final<<<B_ * M_,      256, 0, stream>>>(x, raw, norm, out);
    }
}

// Round 8
// 292.581 us; speedup vs baseline: 1.5700x; 1.3892x over previous
//
#include <hip/hip_runtime.h>
#include <cstdint>
#include <cstddef>

typedef __attribute__((ext_vector_type(8))) unsigned short us8;
typedef __attribute__((ext_vector_type(8))) short short8;
typedef __attribute__((ext_vector_type(4))) float f4v;

#define B_ 4
#define C_ 384
#define H_ 224
#define W_ 224
#define HH 28
#define WW 28
#define HW_ (H_*W_)
#define M_ (HH*WW)
#define SCALE_ 0.05103103630798288f   // 1/sqrt(384)
#define EPS_ 1e-12f

__device__ __forceinline__ unsigned short f2bf(float f) {
    union { float f; unsigned int u; } v; v.f = f;
    unsigned int r = v.u + 0x7FFFu + ((v.u >> 16) & 1u);
    return (unsigned short)(r >> 16);
}
__device__ __forceinline__ float bf2f(unsigned short h) {
    union { unsigned int u; float f; } v; v.u = ((unsigned int)h) << 16;
    return v.f;
}

// ---------------------------------------------------------------------------
// k_tp: layout transform + pool, no LDS. Block = (b, py, cgroup of 32 ch),
// 896 threads = (w 0..223) x (oct 0..3).
// ---------------------------------------------------------------------------
__global__ __launch_bounds__(896) void k_tp(const float* __restrict__ x,
                                            unsigned short* __restrict__ pix,
                                            unsigned short* __restrict__ stokenBF) {
    int bid = blockIdx.x;
    int cg = bid % 12; int t2 = bid / 12; int py = t2 % HH; int b = t2 / HH;
    int tid = threadIdx.x;
    int w = tid >> 2;          // 0..223
    int oct = tid & 3;         // 0..3
    int pxx = w >> 3, qq = w & 7;
    int cbase = cg * 32 + oct * 8;

    const float* xb = x + ((size_t)(b * C_ + cbase) * H_ + py * 8) * W_ + w;
    unsigned short* pb = pix + (((size_t)b * M_ + py * WW + pxx) * 64) * C_ + cbase;

    float v[8][8];   // [pp][j]
    #pragma unroll
    for (int j = 0; j < 8; ++j)
        #pragma unroll
        for (int pp = 0; pp < 8; ++pp)
            v[pp][j] = xb[(size_t)j * HW_ + (size_t)pp * W_];

    #pragma unroll
    for (int pp = 0; pp < 8; ++pp) {
        us8 o;
        #pragma unroll
        for (int j = 0; j < 8; ++j) o[j] = f2bf(v[pp][j]);
        *(us8*)(pb + (size_t)(pp * 8 + qq) * C_) = o;
    }

    float psum[8];
    #pragma unroll
    for (int j = 0; j < 8; ++j) {
        float s = 0.f;
        #pragma unroll
        for (int pp = 0; pp < 8; ++pp) s += v[pp][j];
        s += __shfl_xor(s, 4);
        s += __shfl_xor(s, 8);
        s += __shfl_xor(s, 16);
        psum[j] = s;
    }
    int lane = tid & 63;
    if ((lane & 28) == 0) {    // one lane per (patch, oct)
        us8 o;
        #pragma unroll
        for (int j = 0; j < 8; ++j) o[j] = f2bf(psum[j] * (1.f / 64.f));
        *(us8*)(stokenBF + ((size_t)b * M_ + py * WW + pxx) * C_ + cbase) = o;
    }
}

// ---------------------------------------------------------------------------
// QK via MFMA (m89-verified D mapping: col=lane&15, row=(lane>>4)*4+reg).
// ---------------------------------------------------------------------------
__device__ __forceinline__ f4v qk_wave(const unsigned short* __restrict__ pixP,
                                       const unsigned short* __restrict__ bfbase,
                                       int b, int py, int pxx, int mt) {
    int lane = threadIdx.x & 63;
    int n = lane & 15, g = lane >> 4;
    int yy = py + n / 3 - 1, xx = pxx + n % 3 - 1;
    bool valid = (n < 9) && yy >= 0 && yy < HH && xx >= 0 && xx < WW;
    size_t cell = valid ? ((size_t)b * M_ + (size_t)yy * WW + xx) : 0;
    const unsigned short* bp = bfbase + cell * C_ + g * 8;
    const unsigned short* ap = pixP + (size_t)(mt * 16 + n) * C_ + g * 8;
    const short8 zz = {0, 0, 0, 0, 0, 0, 0, 0};
    f4v acc = {0.f, 0.f, 0.f, 0.f};
    #pragma unroll
    for (int kt = 0; kt < 12; ++kt) {
        short8 a = *(const short8*)(ap + kt * 32);
        short8 bv = *(const short8*)(bp + kt * 32);
        if (!valid) bv = zz;
        acc = __builtin_amdgcn_mfma_f32_16x16x32_bf16(a, bv, acc, 0, 0, 0);
    }
    return acc;
}

__device__ __forceinline__ void softmax_wave(const f4v s, float aout[4]) {
    int lane = threadIdx.x & 63;
    bool coln = (lane & 15) < 9;
    float v[4], e[4], mx[4], su[4];
    #pragma unroll
    for (int r = 0; r < 4; ++r) v[r] = coln ? s[r] * SCALE_ : -3e38f;
    #pragma unroll
    for (int r = 0; r < 4; ++r) mx[r] = v[r];
    #pragma unroll
    for (int d = 1; d < 16; d <<= 1)
        #pragma unroll
        for (int r = 0; r < 4; ++r) mx[r] = fmaxf(mx[r], __shfl_xor(mx[r], d));
    #pragma unroll
    for (int r = 0; r < 4; ++r) e[r] = coln ? __expf(v[r] - mx[r]) : 0.f;
    #pragma unroll
    for (int r = 0; r < 4; ++r) su[r] = e[r];
    #pragma unroll
    for (int d = 1; d < 16; d <<= 1)
        #pragma unroll
        for (int r = 0; r < 4; ++r) su[r] += __shfl_xor(su[r], d);
    #pragma unroll
    for (int r = 0; r < 4; ++r) aout[r] = e[r] / su[r];
}

// ---------------------------------------------------------------------------
// k_it0: iteration 0. Block per (b,patch), 4 waves = 4 M-tiles.
// ---------------------------------------------------------------------------
__global__ __launch_bounds__(256) void k_it0(const unsigned short* __restrict__ pix,
                                             const unsigned short* __restrict__ stokenBF,
                                             float* __restrict__ st_part,
                                             float* __restrict__ normpart) {
    int bid = blockIdx.x;
    int m = bid % M_, b = bid / M_;
    int py = m / WW, pxx = m - py * WW;
    int tid = threadIdx.x;
    int wid = tid >> 6, lane = tid & 63;
    int n = lane & 15, g = lane >> 4;

    __shared__ float aff32[64][12];
    __shared__ float npart[4][16];

    const unsigned short* pixP = pix + (size_t)bid * 64 * C_;
    f4v s = qk_wave(pixP, stokenBF, b, py, pxx, wid);
    float a[4];
    softmax_wave(s, a);

    if (n < 9) {
        #pragma unroll
        for (int r = 0; r < 4; ++r) aff32[wid * 16 + g * 4 + r][n] = a[r];
    }
    float p = a[0] + a[1] + a[2] + a[3];
    p += __shfl_xor(p, 16);
    p += __shfl_xor(p, 32);
    if (lane < 9) npart[wid][lane] = p;
    __syncthreads();

    if (tid < 9)
        normpart[(size_t)bid * 9 + tid] =
            npart[0][tid] + npart[1][tid] + npart[2][tid] + npart[3][tid];

    for (int c = tid; c < C_; c += 256) {
        float acc9[9];
        #pragma unroll
        for (int k = 0; k < 9; ++k) acc9[k] = 0.f;
        const unsigned short* pb = pixP + c;
        for (int l = 0; l < 64; ++l) {
            float pv = bf2f(pb[(size_t)l * C_]);
            const float4* arow = (const float4*)aff32[l];
            float4 a0 = arow[0], a1 = arow[1];
            float a8 = aff32[l][8];
            acc9[0] += pv * a0.x; acc9[1] += pv * a0.y;
            acc9[2] += pv * a0.z; acc9[3] += pv * a0.w;
            acc9[4] += pv * a1.x; acc9[5] += pv * a1.y;
            acc9[6] += pv * a1.z; acc9[7] += pv * a1.w;
            acc9[8] += pv * a8;
        }
        #pragma unroll
        for (int k = 0; k < 9; ++k)
            st_part[((size_t)bid * 9 + k) * C_ + c] = acc9[k];
    }
}

// ---------------------------------------------------------------------------
// k_fold: gather-fold st_part into refined stokens (pre-divided by norm).
// ---------------------------------------------------------------------------
__global__ __launch_bounds__(256) void k_fold(const float* __restrict__ st_part,
                                              const float* __restrict__ normpart,
                                              float* __restrict__ refined,
                                              unsigned short* __restrict__ refinedBF) {
    int bid = blockIdx.x;
    int cell = bid % M_, b = bid / M_;
    int cy = cell / WW, cx = cell - cy * WW;
    int tid = threadIdx.x;

    float nsum = 0.f;
    int srcm[9]; int nsrc = 0;
    #pragma unroll
    for (int nn = 0; nn < 9; ++nn) {
        int my = cy - (nn / 3 - 1), mx = cx - (nn % 3 - 1);
        if (my >= 0 && my < HH && mx >= 0 && mx < WW) {
            int mm = my * WW + mx;
            srcm[nsrc] = mm * 9 + nn;
            nsum += normpart[(size_t)b * M_ * 9 + mm * 9 + nn];
            ++nsrc;
        }
    }
    float inv = 1.f / (nsum + EPS_);
    for (int c = tid; c < C_; c += 256) {
        float s = 0.f;
        for (int k = 0; k < nsrc; ++k)
            s += st_part[((size_t)b * M_ * 9 + srcm[k]) * C_ + c];
        float r = s * inv;
        refined[((size_t)b * M_ + cell) * C_ + c] = r;
        refinedBF[((size_t)b * M_ + cell) * C_ + c] = f2bf(r);
    }
}

// ---------------------------------------------------------------------------
// k_aff: iteration-1 affinity. Writes TRANSPOSED afft[b][py][pp][n][224].
// ---------------------------------------------------------------------------
__global__ __launch_bounds__(256) void k_aff(const unsigned short* __restrict__ pix,
                                             const unsigned short* __restrict__ refinedBF,
                                             float* __restrict__ afft) {
    int bid = blockIdx.x;
    int m = bid % M_, b = bid / M_;
    int py = m / WW, pxx = m - py * WW;
    int tid = threadIdx.x;
    int wid = tid >> 6, lane = tid & 63;
    int n = lane & 15, g = lane >> 4;

    const unsigned short* pixP = pix + (size_t)bid * 64 * C_;
    f4v s = qk_wave(pixP, refinedBF, b, py, pxx, wid);
    float a[4];
    softmax_wave(s, a);

    if (n < 9) {
        #pragma unroll
        for (int r = 0; r < 4; ++r) {
            int l = wid * 16 + g * 4 + r;
            int pp = l >> 3, qq = l & 7;
            afft[((((size_t)b * HH + py) * 8 + pp) * 9 + n) * W_ + pxx * 8 + qq] = a[r];
        }
    }
}

// ---------------------------------------------------------------------------
// k_out v4 = r5 tiling + nontemporal stores + VGPR headroom.
// Block = (b, py, cgroup of 32 ch), 896 threads = (ci 0..3) x (w 0..223).
//  - an[9] per pp from GLOBAL afft (coalesced, L1/L2-broadcast — avoids the
//    LDS-BW ceiling r7 hit with affs-in-LDS: 13.5 -> 4.5 B LDS per output)
//  - stub 11.9 KB LDS, sreg[9][4] hoisted per kh
//  - NONTEMPORAL stores (r7-verified: kills the 300 MB write-allocate fetch)
//  - launch_bounds(896,2): VGPR cap 256 so the ~50 live regs don't spill
// ---------------------------------------------------------------------------
__global__ __launch_bounds__(896, 2) void k_out(const float* __restrict__ refined,
                                                const float* __restrict__ afft,
                                                float* __restrict__ out) {
    int bid = blockIdx.x;
    int cg = bid % 12; int t2 = bid / 12; int py = t2 % HH; int b = t2 / HH;
    int c0 = cg * 32;
    int tid = threadIdx.x;
    int w = tid % 224, ci = tid / 224;
    int pxx = w >> 3;

    __shared__ float stub[3][30][33];
    for (int idx = tid; idx < 3 * 30 * 32; idx += 896) {
        int r = idx / 960; int rem = idx - r * 960;
        int xxp = rem >> 5; int cc = rem & 31;
        int yy = py + r - 1, xx = xxp - 1;
        float v = 0.f;
        if (yy >= 0 && yy < HH && xx >= 0 && xx < WW)
            v = refined[((size_t)b * M_ + yy * WW + xx) * C_ + c0 + cc];
        stub[r][xxp][cc] = v;
    }
    __syncthreads();

    const float* ab = afft + (((size_t)b * HH + py) * 8) * 9 * W_ + w;
    float* obase = out + ((size_t)b * C_ * H_ + (size_t)py * 8) * W_ + w;

    #pragma unroll
    for (int kh = 0; kh < 2; ++kh) {
        float sreg[9][4];
        #pragma unroll
        for (int nn = 0; nn < 9; ++nn)
            #pragma unroll
            for (int k = 0; k < 4; ++k)
                sreg[nn][k] = stub[nn / 3][pxx + nn % 3][ci + (kh * 4 + k) * 4];
        for (int pp = 0; pp < 8; ++pp) {
            float an[9];
            #pragma unroll
            for (int nn = 0; nn < 9; ++nn)
                an[nn] = ab[(size_t)(pp * 9 + nn) * W_];
            #pragma unroll
            for (int k = 0; k < 4; ++k) {
                float s = 0.f;
                #pragma unroll
                for (int nn = 0; nn < 9; ++nn) s += sreg[nn][k] * an[nn];
                __builtin_nontemporal_store(
                    s, &obase[((size_t)(c0 + ci + (kh * 4 + k) * 4) * H_ + pp) * W_]);
            }
        }
    }
}

// ===========================================================================
// Fallback path (round-1 kernels) if ws_size is too small.
// ===========================================================================
__global__ __launch_bounds__(256) void o_pool(const float* __restrict__ x,
                                              float* __restrict__ stoken) {
    int bid = blockIdx.x;
    int yy = bid % HH;
    int t  = bid / HH;
    int c  = t % C_;
    int b  = t / C_;
    __shared__ float colsum[W_];
    int q = threadIdx.x;
    if (q < W_) {
        const float* base = x + ((size_t)(b * C_ + c) * H_ + yy * 8) * W_ + q;
        float s = 0.f;
        #pragma unroll
        for (int p = 0; p < 8; ++p) s += base[(size_t)p * W_];
        colsum[q] = s;
    }
    __syncthreads();
    if (q < WW) {
        float s = 0.f;
        #pragma unroll
        for (int j = 0; j < 8; ++j) s += colsum[q * 8 + j];
        stoken[(((size_t)b * HH + yy) * WW + q) * C_ + c] = s * (1.f / 64.f);
    }
}

__global__ __launch_bounds__(256) void o_iter0(const float* __restrict__ x,
                                               const float* __restrict__ stoken,
                                               float* __restrict__ raw,
                                               float* __restrict__ norm) {
    int bid = blockIdx.x;
    int m = bid % M_;
    int b = bid / M_;
    int py = m / WW, pxx = m % WW;
    int tid = threadIdx.x;
    int w = tid >> 6, l = tid & 63;
    int pp = l >> 3, qq = l & 7;

    __shared__ unsigned short pixs[C_][66];
    __shared__ float sbuf[2304];
    __shared__ float aff[64][10];
    unsigned short* stub = (unsigned short*)sbuf;

    for (int idx = tid; idx < 9 * C_; idx += 256) {
        int nn = idx / C_, c = idx - nn * C_;
        int yy = py + nn / 3 - 1, xx = pxx + nn % 3 - 1;
        float v = 0.f;
        if (yy >= 0 && yy < HH && xx >= 0 && xx < WW)
            v = stoken[(((size_t)b * HH + yy) * WW + xx) * C_ + c];
        stub[idx] = f2bf(v);
    }
    __syncthreads();

    const float* pxbase = x + (size_t)b * C_ * HW_ + (size_t)(py * 8 + pp) * W_ + (pxx * 8 + qq);
    float acc[9];
    #pragma unroll
    for (int nn = 0; nn < 9; ++nn) acc[nn] = 0.f;
    int c0 = w * 96;
    #pragma unroll 4
    for (int c = c0; c < c0 + 96; ++c) {
        float pv = pxbase[(size_t)c * HW_];
        pixs[c][l] = f2bf(pv);
        #pragma unroll
        for (int nn = 0; nn < 9; ++nn) acc[nn] += pv * bf2f(stub[nn * C_ + c]);
    }
    __syncthreads();
    float* qkred = sbuf;
    #pragma unroll
    for (int nn = 0; nn < 9; ++nn) qkred[tid * 9 + nn] = acc[nn];
    __syncthreads();

    if (tid < 64) {
        float s[9];
        #pragma unroll
        for (int nn = 0; nn < 9; ++nn)
            s[nn] = (qkred[(0 * 64 + tid) * 9 + nn] + qkred[(1 * 64 + tid) * 9 + nn] +
                     qkred[(2 * 64 + tid) * 9 + nn] + qkred[(3 * 64 + tid) * 9 + nn]) * SCALE_;
        float mx = s[0];
        #pragma unroll
        for (int nn = 1; nn < 9; ++nn) mx = fmaxf(mx, s[nn]);
        float den = 0.f;
        #pragma unroll
        for (int nn = 0; nn < 9; ++nn) { float e = __expf(s[nn] - mx); den += e; s[nn] = e; }
        float inv = 1.f / den;
        #pragma unroll
        for (int nn = 0; nn < 9; ++nn) aff[tid][nn] = s[nn] * inv;
    }
    __syncthreads();

    if (tid < 9) {
        float s = 0.f;
        for (int ll = 0; ll < 64; ++ll) s += aff[ll][tid];
        int ty = py + tid / 3 - 1, tx = pxx + tid % 3 - 1;
        if (ty >= 0 && ty < HH && tx >= 0 && tx < WW)
            atomicAdd(&norm[((size_t)b * HH + ty) * WW + tx], s);
    }

    for (int c = tid; c < C_; c += 256) {
        float a2[9];
        #pragma unroll
        for (int nn = 0; nn < 9; ++nn) a2[nn] = 0.f;
        for (int ll = 0; ll < 64; ++ll) {
            float pv = bf2f(pixs[c][ll]);
            #pragma unroll
            for (int nn = 0; nn < 9; ++nn) a2[nn] += pv * aff[ll][nn];
        }
        #pragma unroll
        for (int nn = 0; nn < 9; ++nn) {
            int ty = py + nn / 3 - 1, tx = pxx + nn % 3 - 1;
            if (ty >= 0 && ty < HH && tx >= 0 && tx < WW)
                atomicAdd(&raw[(((size_t)b * HH + ty) * WW + tx) * C_ + c], a2[nn]);
        }
    }
}

__global__ __launch_bounds__(256) void o_final(const float* __restrict__ x,
                                               const float* __restrict__ raw,
                                               const float* __restrict__ norm,
                                               float* __restrict__ out) {
    int bid = blockIdx.x;
    int m = bid % M_;
    int b = bid / M_;
    int py = m / WW, pxx = m % WW;
    int tid = threadIdx.x;
    int w = tid >> 6, l = tid & 63;
    int pp = l >> 3, qq = l & 7;

    __shared__ unsigned short stub[9 * C_];
    __shared__ float qkred[4 * 64 * 9];
    __shared__ float aff[64][10];

    for (int idx = tid; idx < 9 * C_; idx += 256) {
        int nn = idx / C_, c = idx - nn * C_;
        int yy = py + nn / 3 - 1, xx = pxx + nn % 3 - 1;
        float v = 0.f;
        if (yy >= 0 && yy < HH && xx >= 0 && xx < WW) {
            size_t cell = ((size_t)b * HH + yy) * WW + xx;
            v = raw[cell * C_ + c] / (norm[cell] + EPS_);
        }
        stub[idx] = f2bf(v);
    }
    __syncthreads();

    const float* pxbase = x + (size_t)b * C_ * HW_ + (size_t)(py * 8 + pp) * W_ + (pxx * 8 + qq);
    float acc[9];
    #pragma unroll
    for (int nn = 0; nn < 9; ++nn) acc[nn] = 0.f;
    int c0 = w * 96;
    #pragma unroll 4
    for (int c = c0; c < c0 + 96; ++c) {
        float pv = pxbase[(size_t)c * HW_];
        #pragma unroll
        for (int nn = 0; nn < 9; ++nn) acc[nn] += pv * bf2f(stub[nn * C_ + c]);
    }
    #pragma unroll
    for (int nn = 0; nn < 9; ++nn) qkred[tid * 9 + nn] = acc[nn];
    __syncthreads();

    if (tid < 64) {
        float s[9];
        #pragma unroll
        for (int nn = 0; nn < 9; ++nn)
            s[nn] = (qkred[(0 * 64 + tid) * 9 + nn] + qkred[(1 * 64 + tid) * 9 + nn] +
                     qkred[(2 * 64 + tid) * 9 + nn] + qkred[(3 * 64 + tid) * 9 + nn]) * SCALE_;
        float mx = s[0];
        #pragma unroll
        for (int nn = 1; nn < 9; ++nn) mx = fmaxf(mx, s[nn]);
        float den = 0.f;
        #pragma unroll
        for (int nn = 0; nn < 9; ++nn) { float e = __expf(s[nn] - mx); den += e; s[nn] = e; }
        float inv = 1.f / den;
        #pragma unroll
        for (int nn = 0; nn < 9; ++nn) aff[tid][nn] = s[nn] * inv;
    }
    __syncthreads();

    float areg[9];
    #pragma unroll
    for (int nn = 0; nn < 9; ++nn) areg[nn] = aff[l][nn];
    float* obase = out + (size_t)b * C_ * HW_ + (size_t)(py * 8 + pp) * W_ + (pxx * 8 + qq);
    #pragma unroll 4
    for (int c = c0; c < c0 + 96; ++c) {
        float v = 0.f;
        #pragma unroll
        for (int nn = 0; nn < 9; ++nn) v += bf2f(stub[nn * C_ + c]) * areg[nn];
        obase[(size_t)c * HW_] = v;
    }
}

extern "C" void kernel_launch(void* const* d_in, const int* in_sizes, int n_in,
                              void* d_out, int out_size, void* d_ws, size_t ws_size,
                              hipStream_t stream) {
    const float* x = (const float*)d_in[0];
    float* out = (float*)d_out;

    const size_t PIXN = (size_t)B_ * M_ * 64 * C_;      // bf16 elements
    const size_t STN  = (size_t)B_ * M_ * C_;           // elements per stoken set
    const size_t AFFN = (size_t)B_ * HH * 8 * 9 * W_;   // fp32 elements (transposed aff)
    const size_t need = PIXN * 2 + STN * 2 + STN * 2
                      + (STN * 10 + (size_t)B_ * M_ * 9 + AFFN) * 4;

    if (ws_size >= need) {
        unsigned short* pix       = (unsigned short*)d_ws;
        unsigned short* stokenBF  = pix + PIXN;
        unsigned short* refinedBF = stokenBF + STN;
        float* st_part  = (float*)(refinedBF + STN);
        float* refined  = st_part + STN * 9;
        float* normpart = refined + STN;
        float* afft     = normpart + (size_t)B_ * M_ * 9;

        k_tp  <<<B_ * HH * 12, 896, 0, stream>>>(x, pix, stokenBF);
        k_it0 <<<B_ * M_,      256, 0, stream>>>(pix, stokenBF, st_part, normpart);
        k_fold<<<B_ * M_,      256, 0, stream>>>(st_part, normpart, refined, refinedBF);
        k_aff <<<B_ * M_,      256, 0, stream>>>(pix, refinedBF, afft);
        k_out <<<B_ * HH * 12, 896, 0, stream>>>(refined, afft, out);
    } else {
        float* stoken = (float*)d_ws;
        float* raw    = stoken + STN;
        float* norm   = raw + STN;
        hipMemsetAsync(raw, 0, STN * sizeof(float), stream);
        hipMemsetAsync(norm, 0, (size_t)B_ * M_ * sizeof(float), stream);
        o_pool <<<B_ * C_ * HH, 256, 0, stream>>>(x, stoken);
        o_iter0<<<B_ * M_,      256, 0, stream>>>(x, stoken, raw, norm);
        o_final<<<B_ * M_,      256, 0, stream>>>(x, raw, norm, out);
    }
}